// Round 2
// baseline (5139.200 us; speedup 1.0000x reference)
//
#include <hip/hip_runtime.h>
#include <stdint.h>

#define BB 64
#define TT 1024
#define HH 512
typedef unsigned long long ull;
typedef float v4f __attribute__((ext_vector_type(4)));
typedef short v8s __attribute__((ext_vector_type(8)));
typedef unsigned v4u __attribute__((ext_vector_type(4)));

__device__ __forceinline__ short f2bf(float f) {
    unsigned u = __float_as_uint(f);
    u += 0x7fffu + ((u >> 16) & 1u);          // RNE to bf16
    return (short)(u >> 16);
}
__device__ __forceinline__ float sigmoidf_(float x) {
    x = fminf(fmaxf(x, -30.f), 30.f);
    return 1.f / (1.f + __expf(-x));
}
__device__ __forceinline__ float tanhf_(float x) {
    x = fminf(fmaxf(x, -15.f), 15.f);
    float e = __expf(2.f * x);
    return (e - 1.f) / (e + 1.f);
}

__device__ __forceinline__ unsigned aload32(const unsigned* p) {
    return __hip_atomic_load(p, __ATOMIC_RELAXED, __HIP_MEMORY_SCOPE_AGENT);
}
__device__ __forceinline__ void wait_ge(unsigned* c, unsigned tgt) {
    while (__hip_atomic_load(c, __ATOMIC_RELAXED, __HIP_MEMORY_SCOPE_AGENT) < tgt)
        __builtin_amdgcn_s_sleep(1);
}
// fire-and-forget tagged store to the device coherence point (no L1/L2 hit)
__device__ __forceinline__ void stcc(unsigned* p, unsigned v) {
    asm volatile("global_store_dword %0, %1, off sc0 sc1" :: "v"(p), "v"(v) : "memory");
}
// 2 chunks (rows m, m+1 at same k): 4 dwordx4 coherent loads, all in flight, one wait
__device__ __forceinline__ void ld4cc(const unsigned* p, v4u& r0, v4u& r1, v4u& r2, v4u& r3) {
    asm volatile(
        "global_load_dwordx4 %0, %4, off sc0 sc1\n\t"
        "global_load_dwordx4 %1, %4, off offset:16 sc0 sc1\n\t"
        "global_load_dwordx4 %2, %4, off offset:2048 sc0 sc1\n\t"
        "global_load_dwordx4 %3, %4, off offset:2064 sc0 sc1\n\t"
        "s_waitcnt vmcnt(0)"
        : "=&v"(r0), "=&v"(r1), "=&v"(r2), "=&v"(r3)
        : "v"(p) : "memory");
}
// issue-only variant: loads left in flight (hidden under following work)
__device__ __forceinline__ void ld4cc_issue(const unsigned* p, v4u& r0, v4u& r1, v4u& r2, v4u& r3) {
    asm volatile(
        "global_load_dwordx4 %0, %4, off sc0 sc1\n\t"
        "global_load_dwordx4 %1, %4, off offset:16 sc0 sc1\n\t"
        "global_load_dwordx4 %2, %4, off offset:2048 sc0 sc1\n\t"
        "global_load_dwordx4 %3, %4, off offset:2064 sc0 sc1"
        : "=&v"(r0), "=&v"(r1), "=&v"(r2), "=&v"(r3)
        : "v"(p) : "memory");
}
// register-tied drain: "+v" ties the probe regs through the waitcnt so no
// consumer of r0..r3 can be scheduled before the wait (rule #18 analog).
__device__ __forceinline__ void vmwait4(v4u& r0, v4u& r1, v4u& r2, v4u& r3) {
    asm volatile("s_waitcnt vmcnt(0)"
        : "+v"(r0), "+v"(r1), "+v"(r2), "+v"(r3) :: "memory");
}
// 4 chunks from two bases (x-part and h-part), 8 loads in flight, one wait
__device__ __forceinline__ void ld8cc(const unsigned* px, const unsigned* ph,
        v4u& x0, v4u& x1, v4u& x2, v4u& x3, v4u& h0, v4u& h1, v4u& h2, v4u& h3) {
    asm volatile(
        "global_load_dwordx4 %0, %8, off sc0 sc1\n\t"
        "global_load_dwordx4 %1, %8, off offset:16 sc0 sc1\n\t"
        "global_load_dwordx4 %2, %8, off offset:2048 sc0 sc1\n\t"
        "global_load_dwordx4 %3, %8, off offset:2064 sc0 sc1\n\t"
        "global_load_dwordx4 %4, %9, off sc0 sc1\n\t"
        "global_load_dwordx4 %5, %9, off offset:16 sc0 sc1\n\t"
        "global_load_dwordx4 %6, %9, off offset:2048 sc0 sc1\n\t"
        "global_load_dwordx4 %7, %9, off offset:2064 sc0 sc1\n\t"
        "s_waitcnt vmcnt(0)"
        : "=&v"(x0), "=&v"(x1), "=&v"(x2), "=&v"(x3),
          "=&v"(h0), "=&v"(h1), "=&v"(h2), "=&v"(h3)
        : "v"(px), "v"(ph) : "memory");
}
__device__ __forceinline__ unsigned tagdiff(v4u a, v4u b, unsigned tg) {
    return ((a.x ^ tg) | (a.y ^ tg) | (a.z ^ tg) | (a.w ^ tg) |
            (b.x ^ tg) | (b.y ^ tg) | (b.z ^ tg) | (b.w ^ tg)) & 0xFFFFu;
}
__device__ __forceinline__ void packlds(short* dst, v4u a, v4u b) {
    v4u d;
    d.x = (a.x >> 16) | (a.y & 0xFFFF0000u);
    d.y = (a.z >> 16) | (a.w & 0xFFFF0000u);
    d.z = (b.x >> 16) | (b.y & 0xFFFF0000u);
    d.w = (b.z >> 16) | (b.w & 0xFFFF0000u);
    *(v4u*)dst = d;
}

// Grid: 128 WGs x 512 threads. WG = (batch-group g, stack s, 32-unit tile).
// Cross-WG sync: tag-in-data polling only; rc1 counter = off-path ib anti-dep.
// Barriers: 2 per step (old 3rd barrier removed). Safety argument:
//  - h-slot overwrite at tau (slot tau&3) is safe because staging at tau
//    observed peer tags tau-1 => peers passed staging tau-1 => peers finished
//    reading slot (tau-3)&3 == tau&3 (sync#1 joins the observation).
//  - ibb slot gated per-thread on rc1 >= 16*(tau-3) (preloaded hint + spin).
//  - s1's i1 read from act_lds is lifted above the MFMA block; cell phase
//    reads no act_lds, so next-iteration staging writes cannot race it.
__global__ __launch_bounds__(512, 1) void lstm_persistent_kernel(
    const float* __restrict__ seq, const int* __restrict__ seq_len,
    const float* __restrict__ W_ih, const float* __restrict__ W_hh,
    const float* __restrict__ b_ih, const float* __restrict__ b_hh,
    float* __restrict__ out, char* __restrict__ ws)
{
    __shared__ __align__(16) short act_lds[2048 * 8];   // 32 KB, A-frag order
    __shared__ float gates_lds[4][16][32];              // 8 KB

    const int gid = blockIdx.x;
    const int g   = gid & 3;
    const int s   = (gid >> 2) & 1;
    const int u0  = (gid >> 3) << 5;
    const int bg  = g << 4;
    const int tid = threadIdx.x;
    const int w   = tid >> 6;
    const int l   = tid & 63;
    const int q   = w >> 1;
    const int uh  = w & 1;
    const int quad = l >> 4, l15 = l & 15;
    const int cb  = tid >> 5, cu = tid & 31;

    unsigned* rc1 = (unsigned*)(ws + g * 256);
    unsigned* h0b = (unsigned*)(ws + 1024);            // [4 slot][4 grp][16][512] tagged u32
    unsigned* h1b = h0b + 4 * 4 * 16 * 512;
    unsigned* ibb = h1b + 4 * 4 * 16 * 512;

    // ---- persistent weights in VGPRs as MFMA B-fragments ----
    const float* Wi = W_ih + (size_t)s * (2048 * 512);
    const float* Wh = W_hh + (size_t)s * (2048 * 512);
    const int row = q * 512 + u0 + uh * 16 + l15;
    v8s wf[32];
#pragma unroll
    for (int kt = 0; kt < 32; ++kt) {
        int ko = kt * 32 + quad * 8;
        const float* p = (ko < 512) ? (Wi + (size_t)row * 512 + ko)
                                    : (Wh + (size_t)row * 512 + (ko - 512));
        float4 x0 = *(const float4*)p;
        float4 x1 = *(const float4*)(p + 4);
        v8s v;
        v[0]=f2bf(x0.x); v[1]=f2bf(x0.y); v[2]=f2bf(x0.z); v[3]=f2bf(x0.w);
        v[4]=f2bf(x1.x); v[5]=f2bf(x1.y); v[6]=f2bf(x1.z); v[7]=f2bf(x1.w);
        wf[kt] = v;
    }
    float bias[4];
#pragma unroll
    for (int qq = 0; qq < 4; ++qq)
        bias[qq] = b_ih[s * 2048 + qq * 512 + u0 + cu] + b_hh[s * 2048 + qq * 512 + u0 + cu];
    const int len = seq_len[bg + cb];
    float hreg = 0.f, creg = 0.f;

    // per-thread chunk geometry (chunk pairs: rows m0,m0+1 at same k-offset)
    const int ch0 = 1024 + (tid << 1);                 // h-part chunk
    const int mh  = ch0 & 15;
    const int kh  = (((ch0 >> 6) << 5) + (((ch0 >> 4) & 3) << 3)) - 512;
    const int cx0 = tid << 1;                          // x-part chunk (s1)
    const int mx  = cx0 & 15;
    const int kx  = ((cx0 >> 6) << 5) + (((cx0 >> 4) & 3) << 3);
    unsigned* myhb = (s == 0) ? h0b : h1b;

    for (int tau = 0; tau <= TT; ++tau) {
        if (s == 0 && tau >= TT) break;
        if (s == 1 && tau == 0) continue;
        const int t   = (s == 0) ? tau : tau - 1;
        const int rb  = (((tau - 1) & 3) << 2 | g) << 13;   // read slot base (u32 idx)
        const int wb  = ((tau & 3) << 2 | g) << 13;         // write slot base
        const unsigned tg = (unsigned)(tau - 1);
        float xres = 0.f;
        unsigned rcv = 0xFFFFFFFFu;

        if (s == 0) {
            // issue the h probe FIRST: its RTT hides under x-staging below
            v4u p0, p1, p2, p3;
            const unsigned* hp = h0b + rb + (mh << 9) + kh;
            if (tau >= 1) ld4cc_issue(hp, p0, p1, p2, p3);
            if (tau >= 4) rcv = aload32(rc1);           // per-thread anti-dep hint
            // x-part from seq (plain loads, no cross-WG dep)
#pragma unroll
            for (int j = 0; j < 2; ++j) {
                int c = (j << 9) + tid;
                int ll = c & 63, m = ll & 15;
                int ko = ((c >> 6) << 5) + ((ll >> 4) << 3);
                const float* p = seq + (((size_t)(bg + m) * TT + t) << 9) + ko;
                float4 x0 = *(const float4*)p, x1 = *(const float4*)(p + 4);
                v8s v;
                v[0]=f2bf(x0.x); v[1]=f2bf(x0.y); v[2]=f2bf(x0.z); v[3]=f2bf(x0.w);
                v[4]=f2bf(x1.x); v[5]=f2bf(x1.y); v[6]=f2bf(x1.z); v[7]=f2bf(x1.w);
                *(v8s*)(act_lds + (size_t)c * 8) = v;
            }
            xres = seq[(((size_t)(bg + cb) * TT + t) << 9) + u0 + cu];
            // h-part: check the early probe, then poll if stale
            if (tau == 0) {
                v4u zz = {0, 0, 0, 0};
                *(v4u*)(act_lds + (size_t)ch0 * 8) = zz;
                *(v4u*)(act_lds + (size_t)(ch0 + 1) * 8) = zz;
            } else {
                vmwait4(p0, p1, p2, p3);
                if ((tagdiff(p0, p1, tg) | tagdiff(p2, p3, tg)) == 0) {
                    packlds(act_lds + (size_t)ch0 * 8, p0, p1);
                    packlds(act_lds + (size_t)(ch0 + 1) * 8, p2, p3);
                } else {
                    for (;;) {
                        v4u r0, r1, r2, r3;
                        ld4cc(hp, r0, r1, r2, r3);
                        if ((tagdiff(r0, r1, tg) | tagdiff(r2, r3, tg)) == 0) {
                            packlds(act_lds + (size_t)ch0 * 8, r0, r1);
                            packlds(act_lds + (size_t)(ch0 + 1) * 8, r2, r3);
                            break;
                        }
                    }
                }
            }
        } else {
            const unsigned* px = ibb + rb + (mx << 9) + kx;
            if (tau == 1) {
                v4u zz = {0, 0, 0, 0};
                *(v4u*)(act_lds + (size_t)ch0 * 8) = zz;
                *(v4u*)(act_lds + (size_t)(ch0 + 1) * 8) = zz;
                for (;;) {
                    v4u r0, r1, r2, r3;
                    ld4cc(px, r0, r1, r2, r3);
                    if ((tagdiff(r0, r1, tg) | tagdiff(r2, r3, tg)) == 0) {
                        packlds(act_lds + (size_t)cx0 * 8, r0, r1);
                        packlds(act_lds + (size_t)(cx0 + 1) * 8, r2, r3);
                        break;
                    }
                }
            } else {
                const unsigned* ph = h1b + rb + (mh << 9) + kh;
                v4u x0, x1, x2, x3, h0, h1, h2, h3;
                ld8cc(px, ph, x0, x1, x2, x3, h0, h1, h2, h3);
                int xok = (tagdiff(x0, x1, tg) | tagdiff(x2, x3, tg)) == 0;
                int hok = (tagdiff(h0, h1, tg) | tagdiff(h2, h3, tg)) == 0;
                if (xok) {
                    packlds(act_lds + (size_t)cx0 * 8, x0, x1);
                    packlds(act_lds + (size_t)(cx0 + 1) * 8, x2, x3);
                }
                if (hok) {
                    packlds(act_lds + (size_t)ch0 * 8, h0, h1);
                    packlds(act_lds + (size_t)(ch0 + 1) * 8, h2, h3);
                }
                while (!(xok & hok)) {                  // reload only stale halves
                    if (!xok & !hok) {
                        ld8cc(px, ph, x0, x1, x2, x3, h0, h1, h2, h3);
                    } else if (!xok) {
                        ld4cc(px, x0, x1, x2, x3);
                    } else {
                        ld4cc(ph, h0, h1, h2, h3);
                    }
                    if (!xok && (tagdiff(x0, x1, tg) | tagdiff(x2, x3, tg)) == 0) {
                        xok = 1;
                        packlds(act_lds + (size_t)cx0 * 8, x0, x1);
                        packlds(act_lds + (size_t)(cx0 + 1) * 8, x2, x3);
                    }
                    if (!hok && (tagdiff(h0, h1, tg) | tagdiff(h2, h3, tg)) == 0) {
                        hok = 1;
                        packlds(act_lds + (size_t)ch0 * 8, h0, h1);
                        packlds(act_lds + (size_t)(ch0 + 1) * 8, h2, h3);
                    }
                }
            }
        }
        __syncthreads();   // sync#1: staging -> MFMA
        if (s == 1 && tid == 0)      // staging done: release ib slot (off-path)
            __hip_atomic_fetch_add(rc1, 1u, __ATOMIC_RELAXED, __HIP_MEMORY_SCOPE_AGENT);
        // s1: lift staged-i1 LDS read above the MFMA block so the cell phase
        // has no act_lds read (required for the removed 3rd barrier).
        float i1v = 0.f;
        if (s == 1) {
            int k  = u0 + cu;
            int cI = ((k >> 5) << 6) + (((k >> 3) & 3) << 4) + cb;
            unsigned short us = (unsigned short)act_lds[cI * 8 + (k & 7)];
            i1v = __uint_as_float(((unsigned)us) << 16);
        }

        // ---- MFMA: gates[16 batch x 16 units] per wave, K=1024 ----
        v4f z = {0.f, 0.f, 0.f, 0.f};
        v4f acc0 = z, acc1 = z, acc2 = z, acc3 = z;
#pragma unroll
        for (int kt = 0; kt < 32; kt += 4) {
            v8s a0 = *(const v8s*)(act_lds + ((kt + 0) * 64 + l) * 8);
            v8s a1 = *(const v8s*)(act_lds + ((kt + 1) * 64 + l) * 8);
            v8s a2 = *(const v8s*)(act_lds + ((kt + 2) * 64 + l) * 8);
            v8s a3 = *(const v8s*)(act_lds + ((kt + 3) * 64 + l) * 8);
            acc0 = __builtin_amdgcn_mfma_f32_16x16x32_bf16(a0, wf[kt + 0], acc0, 0, 0, 0);
            acc1 = __builtin_amdgcn_mfma_f32_16x16x32_bf16(a1, wf[kt + 1], acc1, 0, 0, 0);
            acc2 = __builtin_amdgcn_mfma_f32_16x16x32_bf16(a2, wf[kt + 2], acc2, 0, 0, 0);
            acc3 = __builtin_amdgcn_mfma_f32_16x16x32_bf16(a3, wf[kt + 3], acc3, 0, 0, 0);
        }
        v4f af = (acc0 + acc1) + (acc2 + acc3);
#pragma unroll
        for (int r = 0; r < 4; ++r)
            gates_lds[q][quad * 4 + r][uh * 16 + l15] = af[r];
        __syncthreads();   // sync#2: gates -> cell

        // ---- cell update: thread owns (batch cb, unit cu) ----
        float gi = gates_lds[0][cb][cu] + bias[0];
        float gf = gates_lds[1][cb][cu] + bias[1];
        float gg = gates_lds[2][cb][cu] + bias[2];
        float go = gates_lds[3][cb][cu] + bias[3];
        float ii = sigmoidf_(gi), ff = sigmoidf_(gf);
        float gv = tanhf_(gg),   oo = sigmoidf_(go);
        float cs = ff * creg + ii * gv;
        float hs = oo * tanhf_(cs);
        const bool msk = (t < len);
        if (msk) { creg = cs; hreg = hs; }

        // ---- tagged scatter: h first (critical path), then slack paths ----
        const unsigned otg = (unsigned)tau;
        const int widx = wb + (cb << 9) + u0 + cu;
        stcc(myhb + widx, (((unsigned)(unsigned short)f2bf(hreg)) << 16) | otg);
        if (s == 0) {
            float i1s = hs + xres;                      // candidate residual, per ref
            if (tau >= 4) {                             // per-thread ib slot anti-dep
                unsigned need = 16u * (unsigned)(tau - 3);
                if (rcv < need) wait_ge(rc1, need);
            }
            stcc(ibb + widx, (((unsigned)(unsigned short)f2bf(i1s)) << 16) | otg);
        } else {
            out[(((size_t)(bg + cb) * TT + t) << 9) + u0 + cu] = msk ? (i1v + hs) : 0.f;
        }
        // no 3rd barrier: act_lds re-writes are fenced by sync#2 (MFMA reads)
        // and sync#1 arrival (gates reads); slot reuse by induction / rc1.
    }

    // ---- final h, c ----
    const size_t OH = (size_t)BB * TT * HH;
    const size_t hoff = OH + (size_t)s * BB * HH + ((size_t)(bg + cb) << 9) + u0 + cu;
    out[hoff] = hreg;
    out[hoff + (size_t)2 * BB * HH] = creg;
}

extern "C" void kernel_launch(void* const* d_in, const int* in_sizes, int n_in,
                              void* d_out, int out_size, void* d_ws, size_t ws_size,
                              hipStream_t stream) {
    const float* seq     = (const float*)d_in[0];
    const int*   seq_len = (const int*)d_in[1];
    const float* W_ih    = (const float*)d_in[2];
    const float* W_hh    = (const float*)d_in[3];
    const float* b_ih    = (const float*)d_in[4];
    const float* b_hh    = (const float*)d_in[5];
    float* out = (float*)d_out;

    hipMemsetAsync(d_ws, 0, 1024, stream);   // rc1 counters; data buffers are tag-guarded

    lstm_persistent_kernel<<<dim3(128), dim3(512), 0, stream>>>(
        seq, seq_len, W_ih, W_hh, b_ih, b_hh, out, (char*)d_ws);
}

// Round 3
// 5009.230 us; speedup vs baseline: 1.0259x; 1.0259x over previous
//
#include <hip/hip_runtime.h>
#include <stdint.h>

#define BB 64
#define TT 1024
#define HH 512
typedef unsigned long long ull;
typedef float v4f __attribute__((ext_vector_type(4)));
typedef short v8s __attribute__((ext_vector_type(8)));
typedef unsigned v4u __attribute__((ext_vector_type(4)));

__device__ __forceinline__ short f2bf(float f) {
    unsigned u = __float_as_uint(f);
    u += 0x7fffu + ((u >> 16) & 1u);          // RNE to bf16
    return (short)(u >> 16);
}
__device__ __forceinline__ float sigmoidf_(float x) {
    x = fminf(fmaxf(x, -30.f), 30.f);
    return 1.f / (1.f + __expf(-x));
}
__device__ __forceinline__ float tanhf_(float x) {
    x = fminf(fmaxf(x, -15.f), 15.f);
    float e = __expf(2.f * x);
    return (e - 1.f) / (e + 1.f);
}

__device__ __forceinline__ unsigned aload32(const unsigned* p) {
    return __hip_atomic_load(p, __ATOMIC_RELAXED, __HIP_MEMORY_SCOPE_AGENT);
}
__device__ __forceinline__ void wait_ge(unsigned* c, unsigned tgt) {
    while (__hip_atomic_load(c, __ATOMIC_RELAXED, __HIP_MEMORY_SCOPE_AGENT) < tgt)
        __builtin_amdgcn_s_sleep(1);
}
// fire-and-forget tagged store to the device coherence point (no L1/L2 hit)
__device__ __forceinline__ void stcc(unsigned* p, unsigned v) {
    asm volatile("global_store_dword %0, %1, off sc0 sc1" :: "v"(p), "v"(v) : "memory");
}
// 2 chunks (rows m, m+1 at same k): 4 dwordx4 coherent loads, all in flight, one wait
__device__ __forceinline__ void ld4cc(const unsigned* p, v4u& r0, v4u& r1, v4u& r2, v4u& r3) {
    asm volatile(
        "global_load_dwordx4 %0, %4, off sc0 sc1\n\t"
        "global_load_dwordx4 %1, %4, off offset:16 sc0 sc1\n\t"
        "global_load_dwordx4 %2, %4, off offset:2048 sc0 sc1\n\t"
        "global_load_dwordx4 %3, %4, off offset:2064 sc0 sc1\n\t"
        "s_waitcnt vmcnt(0)"
        : "=&v"(r0), "=&v"(r1), "=&v"(r2), "=&v"(r3)
        : "v"(p) : "memory");
}
// 4 chunks from two bases (x-part and h-part), 8 loads in flight, one wait
__device__ __forceinline__ void ld8cc(const unsigned* px, const unsigned* ph,
        v4u& x0, v4u& x1, v4u& x2, v4u& x3, v4u& h0, v4u& h1, v4u& h2, v4u& h3) {
    asm volatile(
        "global_load_dwordx4 %0, %8, off sc0 sc1\n\t"
        "global_load_dwordx4 %1, %8, off offset:16 sc0 sc1\n\t"
        "global_load_dwordx4 %2, %8, off offset:2048 sc0 sc1\n\t"
        "global_load_dwordx4 %3, %8, off offset:2064 sc0 sc1\n\t"
        "global_load_dwordx4 %4, %9, off sc0 sc1\n\t"
        "global_load_dwordx4 %5, %9, off offset:16 sc0 sc1\n\t"
        "global_load_dwordx4 %6, %9, off offset:2048 sc0 sc1\n\t"
        "global_load_dwordx4 %7, %9, off offset:2064 sc0 sc1\n\t"
        "s_waitcnt vmcnt(0)"
        : "=&v"(x0), "=&v"(x1), "=&v"(x2), "=&v"(x3),
          "=&v"(h0), "=&v"(h1), "=&v"(h2), "=&v"(h3)
        : "v"(px), "v"(ph) : "memory");
}
__device__ __forceinline__ unsigned tagdiff(v4u a, v4u b, unsigned tg) {
    return ((a.x ^ tg) | (a.y ^ tg) | (a.z ^ tg) | (a.w ^ tg) |
            (b.x ^ tg) | (b.y ^ tg) | (b.z ^ tg) | (b.w ^ tg)) & 0xFFFFu;
}
__device__ __forceinline__ void packlds(short* dst, v4u a, v4u b) {
    v4u d;
    d.x = (a.x >> 16) | (a.y & 0xFFFF0000u);
    d.y = (a.z >> 16) | (a.w & 0xFFFF0000u);
    d.z = (b.x >> 16) | (b.y & 0xFFFF0000u);
    d.w = (b.z >> 16) | (b.w & 0xFFFF0000u);
    *(v4u*)dst = d;
}

// Grid: 128 WGs x 512 threads. WG = (batch-group g, stack s, 32-unit tile).
// Baseline (4017us) 3-barrier structure. NEW: wave-granular ready-flags.
// Producer wave w of WG (s,g,tile) stores its h/ib chunks, drains them with a
// per-wave s_waitcnt vmcnt(0) (agent-release pattern), then lane0 stores one
// flag dword = tau+1. Each consumer thread's data chunks come from exactly one
// producer wave (rows 2w,2w+1 of one 32-unit tile), so it spins on that single
// 4B flag (coalesced; a few cache lines total) and only then issues the 64B
// tagged data load -- which then succeeds first-try. Tags remain the ground
// truth (verbatim fallback poll loops), so correctness does not depend on the
// flag/data ordering. Goal: ~16x less coherent poll traffic -> lower LLC
// congestion -> shorter store-visibility + data-load RTTs.
__global__ __launch_bounds__(512, 1) void lstm_persistent_kernel(
    const float* __restrict__ seq, const int* __restrict__ seq_len,
    const float* __restrict__ W_ih, const float* __restrict__ W_hh,
    const float* __restrict__ b_ih, const float* __restrict__ b_hh,
    float* __restrict__ out, char* __restrict__ ws)
{
    __shared__ __align__(16) short act_lds[2048 * 8];   // 32 KB, A-frag order
    __shared__ float gates_lds[4][16][32];              // 8 KB

    const int gid = blockIdx.x;
    const int g   = gid & 3;
    const int s   = (gid >> 2) & 1;
    const int u0  = (gid >> 3) << 5;
    const int bg  = g << 4;
    const int tid = threadIdx.x;
    const int w   = tid >> 6;
    const int l   = tid & 63;
    const int q   = w >> 1;
    const int uh  = w & 1;
    const int quad = l >> 4, l15 = l & 15;
    const int cb  = tid >> 5, cu = tid & 31;

    unsigned* rc1 = (unsigned*)(ws + g * 256);
    unsigned* flg = (unsigned*)(ws + 1024);            // [s 2][g 4][tile 16][wave 8] u32
    unsigned* h0b = (unsigned*)(ws + 8192);            // [4 slot][4 grp][16][512] tagged u32
    unsigned* h1b = h0b + 4 * 4 * 16 * 512;
    unsigned* ibb = h1b + 4 * 4 * 16 * 512;

    // ---- persistent weights in VGPRs as MFMA B-fragments ----
    const float* Wi = W_ih + (size_t)s * (2048 * 512);
    const float* Wh = W_hh + (size_t)s * (2048 * 512);
    const int row = q * 512 + u0 + uh * 16 + l15;
    v8s wf[32];
#pragma unroll
    for (int kt = 0; kt < 32; ++kt) {
        int ko = kt * 32 + quad * 8;
        const float* p = (ko < 512) ? (Wi + (size_t)row * 512 + ko)
                                    : (Wh + (size_t)row * 512 + (ko - 512));
        float4 x0 = *(const float4*)p;
        float4 x1 = *(const float4*)(p + 4);
        v8s v;
        v[0]=f2bf(x0.x); v[1]=f2bf(x0.y); v[2]=f2bf(x0.z); v[3]=f2bf(x0.w);
        v[4]=f2bf(x1.x); v[5]=f2bf(x1.y); v[6]=f2bf(x1.z); v[7]=f2bf(x1.w);
        wf[kt] = v;
    }
    float bias[4];
#pragma unroll
    for (int qq = 0; qq < 4; ++qq)
        bias[qq] = b_ih[s * 2048 + qq * 512 + u0 + cu] + b_hh[s * 2048 + qq * 512 + u0 + cu];
    const int len = seq_len[bg + cb];
    float hreg = 0.f, creg = 0.f;

    // per-thread chunk geometry (chunk pairs: rows m0,m0+1 at same k-offset)
    const int ch0 = 1024 + (tid << 1);                 // h-part chunk
    const int mh  = ch0 & 15;
    const int kh  = (((ch0 >> 6) << 5) + (((ch0 >> 4) & 3) << 3)) - 512;
    const int cx0 = tid << 1;                          // x-part chunk (s1)
    const int mx  = cx0 & 15;
    const int kx  = ((cx0 >> 6) << 5) + (((cx0 >> 4) & 3) << 3);
    unsigned* myhb = (s == 0) ? h0b : h1b;

    // flag addresses (per-thread constants)
    unsigned* fpro = flg + ((((s << 2) | g) << 4 | (gid >> 3)) << 3 | w);   // mine (lane0 stores)
    unsigned* fh   = flg + ((((s << 2) | g) << 4 | (kh >> 5)) << 3 | (mh >> 1)); // h producer wave
    unsigned* fib  = flg + (((g) << 4 | (kx >> 5)) << 3 | (mx >> 1));            // ib producer (s0) wave

    for (int tau = 0; tau <= TT; ++tau) {
        if (s == 0 && tau >= TT) break;
        if (s == 1 && tau == 0) continue;
        const int t   = (s == 0) ? tau : tau - 1;
        const int rb  = (((tau - 1) & 3) << 2 | g) << 13;   // read slot base (u32 idx)
        const int wb  = ((tau & 3) << 2 | g) << 13;         // write slot base
        const unsigned tg = (unsigned)(tau - 1);
        const unsigned ftg = (unsigned)tau;                 // flag target (= tg+1)
        float xres = 0.f;
        unsigned rcv = 0xFFFFFFFFu;

        if (s == 0) {
            if (tid == 0 && tau >= 4) rcv = aload32(rc1);   // preload anti-dep hint
            // x-part from seq (plain loads, no cross-WG dep)
#pragma unroll
            for (int j = 0; j < 2; ++j) {
                int c = (j << 9) + tid;
                int ll = c & 63, m = ll & 15;
                int ko = ((c >> 6) << 5) + ((ll >> 4) << 3);
                const float* p = seq + (((size_t)(bg + m) * TT + t) << 9) + ko;
                float4 x0 = *(const float4*)p, x1 = *(const float4*)(p + 4);
                v8s v;
                v[0]=f2bf(x0.x); v[1]=f2bf(x0.y); v[2]=f2bf(x0.z); v[3]=f2bf(x0.w);
                v[4]=f2bf(x1.x); v[5]=f2bf(x1.y); v[6]=f2bf(x1.z); v[7]=f2bf(x1.w);
                *(v8s*)(act_lds + (size_t)c * 8) = v;
            }
            xres = seq[(((size_t)(bg + cb) * TT + t) << 9) + u0 + cu];
            // h-part: cheap flag front-gate, then tagged data (tag = ground truth)
            if (tau == 0) {
                v4u zz = {0, 0, 0, 0};
                *(v4u*)(act_lds + (size_t)ch0 * 8) = zz;
                *(v4u*)(act_lds + (size_t)(ch0 + 1) * 8) = zz;
            } else {
                while (aload32(fh) < ftg) ;
                const unsigned* hp = h0b + rb + (mh << 9) + kh;
                for (;;) {
                    v4u r0, r1, r2, r3;
                    ld4cc(hp, r0, r1, r2, r3);
                    if ((tagdiff(r0, r1, tg) | tagdiff(r2, r3, tg)) == 0) {
                        packlds(act_lds + (size_t)ch0 * 8, r0, r1);
                        packlds(act_lds + (size_t)(ch0 + 1) * 8, r2, r3);
                        break;
                    }
                }
            }
        } else {
            const unsigned* px = ibb + rb + (mx << 9) + kx;
            if (tau == 1) {
                v4u zz = {0, 0, 0, 0};
                *(v4u*)(act_lds + (size_t)ch0 * 8) = zz;
                *(v4u*)(act_lds + (size_t)(ch0 + 1) * 8) = zz;
                while (aload32(fib) < ftg) ;
                for (;;) {
                    v4u r0, r1, r2, r3;
                    ld4cc(px, r0, r1, r2, r3);
                    if ((tagdiff(r0, r1, tg) | tagdiff(r2, r3, tg)) == 0) {
                        packlds(act_lds + (size_t)cx0 * 8, r0, r1);
                        packlds(act_lds + (size_t)(cx0 + 1) * 8, r2, r3);
                        break;
                    }
                }
            } else {
                while (aload32(fib) < ftg) ;
                while (aload32(fh)  < ftg) ;
                const unsigned* ph = h1b + rb + (mh << 9) + kh;
                for (;;) {
                    v4u x0, x1, x2, x3, h0, h1, h2, h3;
                    ld8cc(px, ph, x0, x1, x2, x3, h0, h1, h2, h3);
                    if ((tagdiff(x0, x1, tg) | tagdiff(x2, x3, tg) |
                         tagdiff(h0, h1, tg) | tagdiff(h2, h3, tg)) == 0) {
                        packlds(act_lds + (size_t)cx0 * 8, x0, x1);
                        packlds(act_lds + (size_t)(cx0 + 1) * 8, x2, x3);
                        packlds(act_lds + (size_t)ch0 * 8, h0, h1);
                        packlds(act_lds + (size_t)(ch0 + 1) * 8, h2, h3);
                        break;
                    }
                }
            }
        }
        __syncthreads();
        if (s == 1 && tid == 0)      // staging done: release ib slot (off-path)
            __hip_atomic_fetch_add(rc1, 1u, __ATOMIC_RELAXED, __HIP_MEMORY_SCOPE_AGENT);

        // ---- MFMA: gates[16 batch x 16 units] per wave, K=1024 ----
        v4f z = {0.f, 0.f, 0.f, 0.f};
        v4f acc0 = z, acc1 = z, acc2 = z, acc3 = z;
#pragma unroll
        for (int kt = 0; kt < 32; kt += 4) {
            v8s a0 = *(const v8s*)(act_lds + ((kt + 0) * 64 + l) * 8);
            v8s a1 = *(const v8s*)(act_lds + ((kt + 1) * 64 + l) * 8);
            v8s a2 = *(const v8s*)(act_lds + ((kt + 2) * 64 + l) * 8);
            v8s a3 = *(const v8s*)(act_lds + ((kt + 3) * 64 + l) * 8);
            acc0 = __builtin_amdgcn_mfma_f32_16x16x32_bf16(a0, wf[kt + 0], acc0, 0, 0, 0);
            acc1 = __builtin_amdgcn_mfma_f32_16x16x32_bf16(a1, wf[kt + 1], acc1, 0, 0, 0);
            acc2 = __builtin_amdgcn_mfma_f32_16x16x32_bf16(a2, wf[kt + 2], acc2, 0, 0, 0);
            acc3 = __builtin_amdgcn_mfma_f32_16x16x32_bf16(a3, wf[kt + 3], acc3, 0, 0, 0);
        }
        v4f af = (acc0 + acc1) + (acc2 + acc3);
#pragma unroll
        for (int r = 0; r < 4; ++r)
            gates_lds[q][quad * 4 + r][uh * 16 + l15] = af[r];
        __syncthreads();

        // ---- cell update: thread owns (batch cb, unit cu) ----
        float gi = gates_lds[0][cb][cu] + bias[0];
        float gf = gates_lds[1][cb][cu] + bias[1];
        float gg = gates_lds[2][cb][cu] + bias[2];
        float go = gates_lds[3][cb][cu] + bias[3];
        float ii = sigmoidf_(gi), ff = sigmoidf_(gf);
        float gv = tanhf_(gg),   oo = sigmoidf_(go);
        float cs = ff * creg + ii * gv;
        float hs = oo * tanhf_(cs);
        const bool msk = (t < len);
        if (msk) { creg = cs; hreg = hs; }
        float i1s = 0.f;
        if (s == 0) {
            i1s = hs + xres;                            // candidate residual, per ref
        } else {
            int k  = u0 + cu;                           // staged bf16 i1 from LDS
            int cI = ((k >> 5) << 6) + (((k >> 3) & 3) << 4) + cb;
            unsigned short us = (unsigned short)act_lds[cI * 8 + (k & 7)];
            float i1 = __uint_as_float(((unsigned)us) << 16);
            out[(((size_t)(bg + cb) * TT + t) << 9) + u0 + cu] = msk ? (i1 + hs) : 0.f;
        }
        if (s == 0 && tid == 0 && tau >= 4) {           // ib slot anti-dep (usually free)
            unsigned need = 16u * (unsigned)(tau - 3);
            if (rcv < need) wait_ge(rc1, need);
        }
        __syncthreads();   // gate stores on anti-dep; also protects act_lds/gates_lds reuse

        // ---- tagged scatter to coherence point, then per-wave release flag ----
        const unsigned otg = (unsigned)tau;
        const int widx = wb + (cb << 9) + u0 + cu;
        if (s == 0) {
            stcc(h0b + widx, (((unsigned)(unsigned short)f2bf(hreg)) << 16) | otg);
            stcc(ibb + widx, (((unsigned)(unsigned short)f2bf(i1s)) << 16) | otg);
        } else {
            stcc(h1b + widx, (((unsigned)(unsigned short)f2bf(hreg)) << 16) | otg);
        }
        // per-wave drain (agent-release) then one flag dword per wave
        asm volatile("s_waitcnt vmcnt(0)" ::: "memory");
        if (l == 0) stcc(fpro, otg + 1u);
    }

    // ---- final h, c ----
    const size_t OH = (size_t)BB * TT * HH;
    const size_t hoff = OH + (size_t)s * BB * HH + ((size_t)(bg + cb) << 9) + u0 + cu;
    out[hoff] = hreg;
    out[hoff + (size_t)2 * BB * HH] = creg;
}

extern "C" void kernel_launch(void* const* d_in, const int* in_sizes, int n_in,
                              void* d_out, int out_size, void* d_ws, size_t ws_size,
                              hipStream_t stream) {
    const float* seq     = (const float*)d_in[0];
    const int*   seq_len = (const int*)d_in[1];
    const float* W_ih    = (const float*)d_in[2];
    const float* W_hh    = (const float*)d_in[3];
    const float* b_ih    = (const float*)d_in[4];
    const float* b_hh    = (const float*)d_in[5];
    float* out = (float*)d_out;

    hipMemsetAsync(d_ws, 0, 8192, stream);   // rc1 counters + wave flags; data is tag-guarded

    lstm_persistent_kernel<<<dim3(128), dim3(512), 0, stream>>>(
        seq, seq_len, W_ih, W_hh, b_ih, b_hh, out, (char*)d_ws);
}

// Round 6
// 4628.028 us; speedup vs baseline: 1.1105x; 1.0824x over previous
//
#include <hip/hip_runtime.h>
#include <stdint.h>

#define BB 64
#define TT 1024
#define HH 512
typedef unsigned long long ull;
typedef float v4f __attribute__((ext_vector_type(4)));
typedef short v8s __attribute__((ext_vector_type(8)));
typedef unsigned v4u __attribute__((ext_vector_type(4)));

__device__ __forceinline__ short f2bf(float f) {
    unsigned u = __float_as_uint(f);
    u += 0x7fffu + ((u >> 16) & 1u);          // RNE to bf16
    return (short)(u >> 16);
}
__device__ __forceinline__ float sigmoidf_(float x) {
    x = fminf(fmaxf(x, -30.f), 30.f);
    return 1.f / (1.f + __expf(-x));
}
__device__ __forceinline__ float tanhf_(float x) {
    x = fminf(fmaxf(x, -15.f), 15.f);
    float e = __expf(2.f * x);
    return (e - 1.f) / (e + 1.f);
}

__device__ __forceinline__ unsigned aload32(const unsigned* p) {
    return __hip_atomic_load(p, __ATOMIC_RELAXED, __HIP_MEMORY_SCOPE_AGENT);
}
__device__ __forceinline__ void wait_ge(unsigned* c, unsigned tgt) {
    while (__hip_atomic_load(c, __ATOMIC_RELAXED, __HIP_MEMORY_SCOPE_AGENT) < tgt)
        __builtin_amdgcn_s_sleep(1);
}
// fire-and-forget tagged store to the device coherence point (no L1/L2 hit)
__device__ __forceinline__ void stcc(unsigned* p, unsigned v) {
    asm volatile("global_store_dword %0, %1, off sc0 sc1" :: "v"(p), "v"(v) : "memory");
}
// 4B coherent probe load (spin body): 16x fewer bytes than the 64B chunk load
__device__ __forceinline__ unsigned ld1cc(const unsigned* p) {
    unsigned r;
    asm volatile(
        "global_load_dword %0, %1, off sc0 sc1\n\t"
        "s_waitcnt vmcnt(0)"
        : "=v"(r) : "v"(p) : "memory");
    return r;
}
// dual 4B coherent probe (s1: one dword from ibb, one from h1b), single wait
__device__ __forceinline__ void ld2cc(const unsigned* a, const unsigned* b,
                                      unsigned& ra, unsigned& rb2) {
    asm volatile(
        "global_load_dword %0, %2, off sc0 sc1\n\t"
        "global_load_dword %1, %3, off sc0 sc1\n\t"
        "s_waitcnt vmcnt(0)"
        : "=&v"(ra), "=&v"(rb2) : "v"(a), "v"(b) : "memory");
}
// 2 chunks (rows m, m+1 at same k): 4 dwordx4 coherent loads, all in flight, one wait
__device__ __forceinline__ void ld4cc(const unsigned* p, v4u& r0, v4u& r1, v4u& r2, v4u& r3) {
    asm volatile(
        "global_load_dwordx4 %0, %4, off sc0 sc1\n\t"
        "global_load_dwordx4 %1, %4, off offset:16 sc0 sc1\n\t"
        "global_load_dwordx4 %2, %4, off offset:2048 sc0 sc1\n\t"
        "global_load_dwordx4 %3, %4, off offset:2064 sc0 sc1\n\t"
        "s_waitcnt vmcnt(0)"
        : "=&v"(r0), "=&v"(r1), "=&v"(r2), "=&v"(r3)
        : "v"(p) : "memory");
}
// 4 chunks from two bases (x-part and h-part), 8 loads in flight, one wait
__device__ __forceinline__ void ld8cc(const unsigned* px, const unsigned* ph,
        v4u& x0, v4u& x1, v4u& x2, v4u& x3, v4u& h0, v4u& h1, v4u& h2, v4u& h3) {
    asm volatile(
        "global_load_dwordx4 %0, %8, off sc0 sc1\n\t"
        "global_load_dwordx4 %1, %8, off offset:16 sc0 sc1\n\t"
        "global_load_dwordx4 %2, %8, off offset:2048 sc0 sc1\n\t"
        "global_load_dwordx4 %3, %8, off offset:2064 sc0 sc1\n\t"
        "global_load_dwordx4 %4, %9, off sc0 sc1\n\t"
        "global_load_dwordx4 %5, %9, off offset:16 sc0 sc1\n\t"
        "global_load_dwordx4 %6, %9, off offset:2048 sc0 sc1\n\t"
        "global_load_dwordx4 %7, %9, off offset:2064 sc0 sc1\n\t"
        "s_waitcnt vmcnt(0)"
        : "=&v"(x0), "=&v"(x1), "=&v"(x2), "=&v"(x3),
          "=&v"(h0), "=&v"(h1), "=&v"(h2), "=&v"(h3)
        : "v"(px), "v"(ph) : "memory");
}
__device__ __forceinline__ unsigned tagdiff(v4u a, v4u b, unsigned tg) {
    return ((a.x ^ tg) | (a.y ^ tg) | (a.z ^ tg) | (a.w ^ tg) |
            (b.x ^ tg) | (b.y ^ tg) | (b.z ^ tg) | (b.w ^ tg)) & 0xFFFFu;
}
__device__ __forceinline__ void packlds(short* dst, v4u a, v4u b) {
    v4u d;
    d.x = (a.x >> 16) | (a.y & 0xFFFF0000u);
    d.y = (a.z >> 16) | (a.w & 0xFFFF0000u);
    d.z = (b.x >> 16) | (b.y & 0xFFFF0000u);
    d.w = (b.z >> 16) | (b.w & 0xFFFF0000u);
    *(v4u*)dst = d;
}

// Grid: 128 WGs x 512 threads. WG = (batch-group g, stack s, 32-unit tile).
// Exact 4017us baseline structure (3 barriers, tag-in-data, no producer drain).
// ONE change vs baseline: spin loops probe a single 4B tagged dword per thread
// (the thread's chunk-base dword) instead of re-issuing the full 64B/128B
// tagged load each iteration. Full tagged load + verify loop (unchanged
// baseline code) runs only after the probe's tag matches. The 16 dwords of a
// chunk are stored back-to-back by one producer wave, so verify succeeds
// first-try; any straggler falls back to the baseline loop. Goal: ~16x fewer
// coherent spin bytes -> decongest the fabric -> shorter store-visibility and
// load RTTs on the serial recurrence chain.
__global__ __launch_bounds__(512, 1) void lstm_persistent_kernel(
    const float* __restrict__ seq, const int* __restrict__ seq_len,
    const float* __restrict__ W_ih, const float* __restrict__ W_hh,
    const float* __restrict__ b_ih, const float* __restrict__ b_hh,
    float* __restrict__ out, char* __restrict__ ws)
{
    __shared__ __align__(16) short act_lds[2048 * 8];   // 32 KB, A-frag order
    __shared__ float gates_lds[4][16][32];              // 8 KB

    const int gid = blockIdx.x;
    const int g   = gid & 3;
    const int s   = (gid >> 2) & 1;
    const int u0  = (gid >> 3) << 5;
    const int bg  = g << 4;
    const int tid = threadIdx.x;
    const int w   = tid >> 6;
    const int l   = tid & 63;
    const int q   = w >> 1;
    const int uh  = w & 1;
    const int quad = l >> 4, l15 = l & 15;
    const int cb  = tid >> 5, cu = tid & 31;

    unsigned* rc1 = (unsigned*)(ws + g * 256);
    unsigned* h0b = (unsigned*)(ws + 1024);            // [4 slot][4 grp][16][512] tagged u32
    unsigned* h1b = h0b + 4 * 4 * 16 * 512;
    unsigned* ibb = h1b + 4 * 4 * 16 * 512;

    // ---- persistent weights in VGPRs as MFMA B-fragments ----
    const float* Wi = W_ih + (size_t)s * (2048 * 512);
    const float* Wh = W_hh + (size_t)s * (2048 * 512);
    const int row = q * 512 + u0 + uh * 16 + l15;
    v8s wf[32];
#pragma unroll
    for (int kt = 0; kt < 32; ++kt) {
        int ko = kt * 32 + quad * 8;
        const float* p = (ko < 512) ? (Wi + (size_t)row * 512 + ko)
                                    : (Wh + (size_t)row * 512 + (ko - 512));
        float4 x0 = *(const float4*)p;
        float4 x1 = *(const float4*)(p + 4);
        v8s v;
        v[0]=f2bf(x0.x); v[1]=f2bf(x0.y); v[2]=f2bf(x0.z); v[3]=f2bf(x0.w);
        v[4]=f2bf(x1.x); v[5]=f2bf(x1.y); v[6]=f2bf(x1.z); v[7]=f2bf(x1.w);
        wf[kt] = v;
    }
    float bias[4];
#pragma unroll
    for (int qq = 0; qq < 4; ++qq)
        bias[qq] = b_ih[s * 2048 + qq * 512 + u0 + cu] + b_hh[s * 2048 + qq * 512 + u0 + cu];
    const int len = seq_len[bg + cb];
    float hreg = 0.f, creg = 0.f;

    // per-thread chunk geometry (chunk pairs: rows m0,m0+1 at same k-offset)
    const int ch0 = 1024 + (tid << 1);                 // h-part chunk
    const int mh  = ch0 & 15;
    const int kh  = (((ch0 >> 6) << 5) + (((ch0 >> 4) & 3) << 3)) - 512;
    const int cx0 = tid << 1;                          // x-part chunk (s1)
    const int mx  = cx0 & 15;
    const int kx  = ((cx0 >> 6) << 5) + (((cx0 >> 4) & 3) << 3);
    unsigned* myhb = (s == 0) ? h0b : h1b;

    for (int tau = 0; tau <= TT; ++tau) {
        if (s == 0 && tau >= TT) break;
        if (s == 1 && tau == 0) continue;
        const int t   = (s == 0) ? tau : tau - 1;
        const int rb  = (((tau - 1) & 3) << 2 | g) << 13;   // read slot base (u32 idx)
        const int wb  = ((tau & 3) << 2 | g) << 13;         // write slot base
        const unsigned tg = (unsigned)(tau - 1);
        float xres = 0.f;
        unsigned rcv = 0xFFFFFFFFu;

        if (s == 0) {
            if (tid == 0 && tau >= 4) rcv = aload32(rc1);   // preload anti-dep hint
            // x-part from seq (plain loads, no cross-WG dep)
#pragma unroll
            for (int j = 0; j < 2; ++j) {
                int c = (j << 9) + tid;
                int ll = c & 63, m = ll & 15;
                int ko = ((c >> 6) << 5) + ((ll >> 4) << 3);
                const float* p = seq + (((size_t)(bg + m) * TT + t) << 9) + ko;
                float4 x0 = *(const float4*)p, x1 = *(const float4*)(p + 4);
                v8s v;
                v[0]=f2bf(x0.x); v[1]=f2bf(x0.y); v[2]=f2bf(x0.z); v[3]=f2bf(x0.w);
                v[4]=f2bf(x1.x); v[5]=f2bf(x1.y); v[6]=f2bf(x1.z); v[7]=f2bf(x1.w);
                *(v8s*)(act_lds + (size_t)c * 8) = v;
            }
            xres = seq[(((size_t)(bg + cb) * TT + t) << 9) + u0 + cu];
            // h-part: 4B probe spin, then full tagged load (baseline verify loop)
            if (tau == 0) {
                v4u zz = {0, 0, 0, 0};
                *(v4u*)(act_lds + (size_t)ch0 * 8) = zz;
                *(v4u*)(act_lds + (size_t)(ch0 + 1) * 8) = zz;
            } else {
                const unsigned* hp = h0b + rb + (mh << 9) + kh;
                while ((ld1cc(hp) ^ tg) & 0xFFFFu) ;
                for (;;) {
                    v4u r0, r1, r2, r3;
                    ld4cc(hp, r0, r1, r2, r3);
                    if ((tagdiff(r0, r1, tg) | tagdiff(r2, r3, tg)) == 0) {
                        packlds(act_lds + (size_t)ch0 * 8, r0, r1);
                        packlds(act_lds + (size_t)(ch0 + 1) * 8, r2, r3);
                        break;
                    }
                }
            }
        } else {
            const unsigned* px = ibb + rb + (mx << 9) + kx;
            if (tau == 1) {
                v4u zz = {0, 0, 0, 0};
                *(v4u*)(act_lds + (size_t)ch0 * 8) = zz;
                *(v4u*)(act_lds + (size_t)(ch0 + 1) * 8) = zz;
                while ((ld1cc(px) ^ tg) & 0xFFFFu) ;
                for (;;) {
                    v4u r0, r1, r2, r3;
                    ld4cc(px, r0, r1, r2, r3);
                    if ((tagdiff(r0, r1, tg) | tagdiff(r2, r3, tg)) == 0) {
                        packlds(act_lds + (size_t)cx0 * 8, r0, r1);
                        packlds(act_lds + (size_t)(cx0 + 1) * 8, r2, r3);
                        break;
                    }
                }
            } else {
                const unsigned* ph = h1b + rb + (mh << 9) + kh;
                unsigned pa, pb;
                do { ld2cc(px, ph, pa, pb); } while (((pa ^ tg) | (pb ^ tg)) & 0xFFFFu);
                for (;;) {
                    v4u x0, x1, x2, x3, h0, h1, h2, h3;
                    ld8cc(px, ph, x0, x1, x2, x3, h0, h1, h2, h3);
                    if ((tagdiff(x0, x1, tg) | tagdiff(x2, x3, tg) |
                         tagdiff(h0, h1, tg) | tagdiff(h2, h3, tg)) == 0) {
                        packlds(act_lds + (size_t)cx0 * 8, x0, x1);
                        packlds(act_lds + (size_t)(cx0 + 1) * 8, x2, x3);
                        packlds(act_lds + (size_t)ch0 * 8, h0, h1);
                        packlds(act_lds + (size_t)(ch0 + 1) * 8, h2, h3);
                        break;
                    }
                }
            }
        }
        __syncthreads();
        if (s == 1 && tid == 0)      // staging done: release ib slot (off-path)
            __hip_atomic_fetch_add(rc1, 1u, __ATOMIC_RELAXED, __HIP_MEMORY_SCOPE_AGENT);

        // ---- MFMA: gates[16 batch x 16 units] per wave, K=1024 ----
        v4f z = {0.f, 0.f, 0.f, 0.f};
        v4f acc0 = z, acc1 = z, acc2 = z, acc3 = z;
#pragma unroll
        for (int kt = 0; kt < 32; kt += 4) {
            v8s a0 = *(const v8s*)(act_lds + ((kt + 0) * 64 + l) * 8);
            v8s a1 = *(const v8s*)(act_lds + ((kt + 1) * 64 + l) * 8);
            v8s a2 = *(const v8s*)(act_lds + ((kt + 2) * 64 + l) * 8);
            v8s a3 = *(const v8s*)(act_lds + ((kt + 3) * 64 + l) * 8);
            acc0 = __builtin_amdgcn_mfma_f32_16x16x32_bf16(a0, wf[kt + 0], acc0, 0, 0, 0);
            acc1 = __builtin_amdgcn_mfma_f32_16x16x32_bf16(a1, wf[kt + 1], acc1, 0, 0, 0);
            acc2 = __builtin_amdgcn_mfma_f32_16x16x32_bf16(a2, wf[kt + 2], acc2, 0, 0, 0);
            acc3 = __builtin_amdgcn_mfma_f32_16x16x32_bf16(a3, wf[kt + 3], acc3, 0, 0, 0);
        }
        v4f af = (acc0 + acc1) + (acc2 + acc3);
#pragma unroll
        for (int r = 0; r < 4; ++r)
            gates_lds[q][quad * 4 + r][uh * 16 + l15] = af[r];
        __syncthreads();

        // ---- cell update: thread owns (batch cb, unit cu) ----
        float gi = gates_lds[0][cb][cu] + bias[0];
        float gf = gates_lds[1][cb][cu] + bias[1];
        float gg = gates_lds[2][cb][cu] + bias[2];
        float go = gates_lds[3][cb][cu] + bias[3];
        float ii = sigmoidf_(gi), ff = sigmoidf_(gf);
        float gv = tanhf_(gg),   oo = sigmoidf_(go);
        float cs = ff * creg + ii * gv;
        float hs = oo * tanhf_(cs);
        const bool msk = (t < len);
        if (msk) { creg = cs; hreg = hs; }
        float i1s = 0.f;
        if (s == 0) {
            i1s = hs + xres;                            // candidate residual, per ref
        } else {
            int k  = u0 + cu;                           // staged bf16 i1 from LDS
            int cI = ((k >> 5) << 6) + (((k >> 3) & 3) << 4) + cb;
            unsigned short us = (unsigned short)act_lds[cI * 8 + (k & 7)];
            float i1 = __uint_as_float(((unsigned)us) << 16);
            out[(((size_t)(bg + cb) * TT + t) << 9) + u0 + cu] = msk ? (i1 + hs) : 0.f;
        }
        if (s == 0 && tid == 0 && tau >= 4) {           // ib slot anti-dep (usually free)
            unsigned need = 16u * (unsigned)(tau - 3);
            if (rcv < need) wait_ge(rc1, need);
        }
        __syncthreads();   // gate stores on anti-dep; also protects act_lds/gates_lds reuse

        // ---- tagged scatter to coherence point (fire-and-forget) ----
        const unsigned otg = (unsigned)tau;
        const int widx = wb + (cb << 9) + u0 + cu;
        if (s == 0) {
            stcc(h0b + widx, (((unsigned)(unsigned short)f2bf(hreg)) << 16) | otg);
            stcc(ibb + widx, (((unsigned)(unsigned short)f2bf(i1s)) << 16) | otg);
        } else {
            stcc(h1b + widx, (((unsigned)(unsigned short)f2bf(hreg)) << 16) | otg);
        }
    }

    // ---- final h, c ----
    const size_t OH = (size_t)BB * TT * HH;
    const size_t hoff = OH + (size_t)s * BB * HH + ((size_t)(bg + cb) << 9) + u0 + cu;
    out[hoff] = hreg;
    out[hoff + (size_t)2 * BB * HH] = creg;
}

extern "C" void kernel_launch(void* const* d_in, const int* in_sizes, int n_in,
                              void* d_out, int out_size, void* d_ws, size_t ws_size,
                              hipStream_t stream) {
    const float* seq     = (const float*)d_in[0];
    const int*   seq_len = (const int*)d_in[1];
    const float* W_ih    = (const float*)d_in[2];
    const float* W_hh    = (const float*)d_in[3];
    const float* b_ih    = (const float*)d_in[4];
    const float* b_hh    = (const float*)d_in[5];
    float* out = (float*)d_out;

    hipMemsetAsync(d_ws, 0, 1024, stream);   // rc1 counters; data buffers are tag-guarded

    lstm_persistent_kernel<<<dim3(128), dim3(512), 0, stream>>>(
        seq, seq_len, W_ih, W_hh, b_ih, b_hh, out, (char*)d_ws);
}

// Round 9
// 4025.337 us; speedup vs baseline: 1.2767x; 1.1497x over previous
//
#include <hip/hip_runtime.h>
#include <stdint.h>

#define BB 64
#define TT 1024
#define HH 512
typedef unsigned long long ull;
typedef float v4f __attribute__((ext_vector_type(4)));
typedef short v8s __attribute__((ext_vector_type(8)));
typedef unsigned v4u __attribute__((ext_vector_type(4)));

__device__ __forceinline__ short f2bf(float f) {
    unsigned u = __float_as_uint(f);
    u += 0x7fffu + ((u >> 16) & 1u);          // RNE to bf16
    return (short)(u >> 16);
}
__device__ __forceinline__ float sigmoidf_(float x) {
    x = fminf(fmaxf(x, -30.f), 30.f);
    return 1.f / (1.f + __expf(-x));
}
__device__ __forceinline__ float tanhf_(float x) {
    x = fminf(fmaxf(x, -15.f), 15.f);
    float e = __expf(2.f * x);
    return (e - 1.f) / (e + 1.f);
}

__device__ __forceinline__ unsigned aload32(const unsigned* p) {
    return __hip_atomic_load(p, __ATOMIC_RELAXED, __HIP_MEMORY_SCOPE_AGENT);
}
__device__ __forceinline__ void wait_ge(unsigned* c, unsigned tgt) {
    while (__hip_atomic_load(c, __ATOMIC_RELAXED, __HIP_MEMORY_SCOPE_AGENT) < tgt)
        __builtin_amdgcn_s_sleep(1);
}
// fire-and-forget tagged store to the device coherence point (no L1/L2 hit)
__device__ __forceinline__ void stcc(unsigned* p, unsigned v) {
    asm volatile("global_store_dword %0, %1, off sc0 sc1" :: "v"(p), "v"(v) : "memory");
}
// 2 chunks (rows m, m+1 at same k): 4 dwordx4 coherent loads, all in flight, one wait
__device__ __forceinline__ void ld4cc(const unsigned* p, v4u& r0, v4u& r1, v4u& r2, v4u& r3) {
    asm volatile(
        "global_load_dwordx4 %0, %4, off sc0 sc1\n\t"
        "global_load_dwordx4 %1, %4, off offset:16 sc0 sc1\n\t"
        "global_load_dwordx4 %2, %4, off offset:2048 sc0 sc1\n\t"
        "global_load_dwordx4 %3, %4, off offset:2064 sc0 sc1\n\t"
        "s_waitcnt vmcnt(0)"
        : "=&v"(r0), "=&v"(r1), "=&v"(r2), "=&v"(r3)
        : "v"(p) : "memory");
}
// 4 chunks from two bases (x-part and h-part), 8 loads in flight, one wait
__device__ __forceinline__ void ld8cc(const unsigned* px, const unsigned* ph,
        v4u& x0, v4u& x1, v4u& x2, v4u& x3, v4u& h0, v4u& h1, v4u& h2, v4u& h3) {
    asm volatile(
        "global_load_dwordx4 %0, %8, off sc0 sc1\n\t"
        "global_load_dwordx4 %1, %8, off offset:16 sc0 sc1\n\t"
        "global_load_dwordx4 %2, %8, off offset:2048 sc0 sc1\n\t"
        "global_load_dwordx4 %3, %8, off offset:2064 sc0 sc1\n\t"
        "global_load_dwordx4 %4, %9, off sc0 sc1\n\t"
        "global_load_dwordx4 %5, %9, off offset:16 sc0 sc1\n\t"
        "global_load_dwordx4 %6, %9, off offset:2048 sc0 sc1\n\t"
        "global_load_dwordx4 %7, %9, off offset:2064 sc0 sc1\n\t"
        "s_waitcnt vmcnt(0)"
        : "=&v"(x0), "=&v"(x1), "=&v"(x2), "=&v"(x3),
          "=&v"(h0), "=&v"(h1), "=&v"(h2), "=&v"(h3)
        : "v"(px), "v"(ph) : "memory");
}
__device__ __forceinline__ unsigned tagdiff(v4u a, v4u b, unsigned tg) {
    return ((a.x ^ tg) | (a.y ^ tg) | (a.z ^ tg) | (a.w ^ tg) |
            (b.x ^ tg) | (b.y ^ tg) | (b.z ^ tg) | (b.w ^ tg)) & 0xFFFFu;
}
__device__ __forceinline__ void packlds(short* dst, v4u a, v4u b) {
    v4u d;
    d.x = (a.x >> 16) | (a.y & 0xFFFF0000u);
    d.y = (a.z >> 16) | (a.w & 0xFFFF0000u);
    d.z = (b.x >> 16) | (b.y & 0xFFFF0000u);
    d.w = (b.z >> 16) | (b.w & 0xFFFF0000u);
    *(v4u*)dst = d;
}

// Grid: 128 WGs x 512 threads. WG = (batch-group g, stack s, 32-unit tile).
// Exact 4017us baseline (3 barriers, full-payload tag polls, probe-spin
// reverted). ONE change: the h-store is issued immediately after the cell
// update, BEFORE the rc1 gate and barrier#3, taking ~300-600cy of gate+join
// off the h store-visibility edge of the cross-WG recurrence. Safety (slot
// tau&3 overwrites data tau-4): during staging of step tau we observed tag
// tau-1 from every peer (the WG's 512 threads collectively poll all 16
// producer tiles; barrier#1 joins the observation) => every peer completed
// step tau-1 => passed staging tau-3 => finished reading the slot we now
// overwrite. The ibb store keeps its rc1 gate + barrier#3 (s1-consumption
// anti-dep) exactly as baseline.
__global__ __launch_bounds__(512, 1) void lstm_persistent_kernel(
    const float* __restrict__ seq, const int* __restrict__ seq_len,
    const float* __restrict__ W_ih, const float* __restrict__ W_hh,
    const float* __restrict__ b_ih, const float* __restrict__ b_hh,
    float* __restrict__ out, char* __restrict__ ws)
{
    __shared__ __align__(16) short act_lds[2048 * 8];   // 32 KB, A-frag order
    __shared__ float gates_lds[4][16][32];              // 8 KB

    const int gid = blockIdx.x;
    const int g   = gid & 3;
    const int s   = (gid >> 2) & 1;
    const int u0  = (gid >> 3) << 5;
    const int bg  = g << 4;
    const int tid = threadIdx.x;
    const int w   = tid >> 6;
    const int l   = tid & 63;
    const int q   = w >> 1;
    const int uh  = w & 1;
    const int quad = l >> 4, l15 = l & 15;
    const int cb  = tid >> 5, cu = tid & 31;

    unsigned* rc1 = (unsigned*)(ws + g * 256);
    unsigned* h0b = (unsigned*)(ws + 1024);            // [4 slot][4 grp][16][512] tagged u32
    unsigned* h1b = h0b + 4 * 4 * 16 * 512;
    unsigned* ibb = h1b + 4 * 4 * 16 * 512;

    // ---- persistent weights in VGPRs as MFMA B-fragments ----
    const float* Wi = W_ih + (size_t)s * (2048 * 512);
    const float* Wh = W_hh + (size_t)s * (2048 * 512);
    const int row = q * 512 + u0 + uh * 16 + l15;
    v8s wf[32];
#pragma unroll
    for (int kt = 0; kt < 32; ++kt) {
        int ko = kt * 32 + quad * 8;
        const float* p = (ko < 512) ? (Wi + (size_t)row * 512 + ko)
                                    : (Wh + (size_t)row * 512 + (ko - 512));
        float4 x0 = *(const float4*)p;
        float4 x1 = *(const float4*)(p + 4);
        v8s v;
        v[0]=f2bf(x0.x); v[1]=f2bf(x0.y); v[2]=f2bf(x0.z); v[3]=f2bf(x0.w);
        v[4]=f2bf(x1.x); v[5]=f2bf(x1.y); v[6]=f2bf(x1.z); v[7]=f2bf(x1.w);
        wf[kt] = v;
    }
    float bias[4];
#pragma unroll
    for (int qq = 0; qq < 4; ++qq)
        bias[qq] = b_ih[s * 2048 + qq * 512 + u0 + cu] + b_hh[s * 2048 + qq * 512 + u0 + cu];
    const int len = seq_len[bg + cb];
    float hreg = 0.f, creg = 0.f;

    // per-thread chunk geometry (chunk pairs: rows m0,m0+1 at same k-offset)
    const int ch0 = 1024 + (tid << 1);                 // h-part chunk
    const int mh  = ch0 & 15;
    const int kh  = (((ch0 >> 6) << 5) + (((ch0 >> 4) & 3) << 3)) - 512;
    const int cx0 = tid << 1;                          // x-part chunk (s1)
    const int mx  = cx0 & 15;
    const int kx  = ((cx0 >> 6) << 5) + (((cx0 >> 4) & 3) << 3);
    unsigned* myhb = (s == 0) ? h0b : h1b;

    for (int tau = 0; tau <= TT; ++tau) {
        if (s == 0 && tau >= TT) break;
        if (s == 1 && tau == 0) continue;
        const int t   = (s == 0) ? tau : tau - 1;
        const int rb  = (((tau - 1) & 3) << 2 | g) << 13;   // read slot base (u32 idx)
        const int wb  = ((tau & 3) << 2 | g) << 13;         // write slot base
        const unsigned tg = (unsigned)(tau - 1);
        float xres = 0.f;
        unsigned rcv = 0xFFFFFFFFu;

        if (s == 0) {
            if (tid == 0 && tau >= 4) rcv = aload32(rc1);   // preload anti-dep hint
            // x-part from seq (plain loads, no cross-WG dep)
#pragma unroll
            for (int j = 0; j < 2; ++j) {
                int c = (j << 9) + tid;
                int ll = c & 63, m = ll & 15;
                int ko = ((c >> 6) << 5) + ((ll >> 4) << 3);
                const float* p = seq + (((size_t)(bg + m) * TT + t) << 9) + ko;
                float4 x0 = *(const float4*)p, x1 = *(const float4*)(p + 4);
                v8s v;
                v[0]=f2bf(x0.x); v[1]=f2bf(x0.y); v[2]=f2bf(x0.z); v[3]=f2bf(x0.w);
                v[4]=f2bf(x1.x); v[5]=f2bf(x1.y); v[6]=f2bf(x1.z); v[7]=f2bf(x1.w);
                *(v8s*)(act_lds + (size_t)c * 8) = v;
            }
            xres = seq[(((size_t)(bg + cb) * TT + t) << 9) + u0 + cu];
            // h-part: poll own-group tagged data
            if (tau == 0) {
                v4u zz = {0, 0, 0, 0};
                *(v4u*)(act_lds + (size_t)ch0 * 8) = zz;
                *(v4u*)(act_lds + (size_t)(ch0 + 1) * 8) = zz;
            } else {
                const unsigned* hp = h0b + rb + (mh << 9) + kh;
                for (;;) {
                    v4u r0, r1, r2, r3;
                    ld4cc(hp, r0, r1, r2, r3);
                    if ((tagdiff(r0, r1, tg) | tagdiff(r2, r3, tg)) == 0) {
                        packlds(act_lds + (size_t)ch0 * 8, r0, r1);
                        packlds(act_lds + (size_t)(ch0 + 1) * 8, r2, r3);
                        break;
                    }
                }
            }
        } else {
            const unsigned* px = ibb + rb + (mx << 9) + kx;
            if (tau == 1) {
                v4u zz = {0, 0, 0, 0};
                *(v4u*)(act_lds + (size_t)ch0 * 8) = zz;
                *(v4u*)(act_lds + (size_t)(ch0 + 1) * 8) = zz;
                for (;;) {
                    v4u r0, r1, r2, r3;
                    ld4cc(px, r0, r1, r2, r3);
                    if ((tagdiff(r0, r1, tg) | tagdiff(r2, r3, tg)) == 0) {
                        packlds(act_lds + (size_t)cx0 * 8, r0, r1);
                        packlds(act_lds + (size_t)(cx0 + 1) * 8, r2, r3);
                        break;
                    }
                }
            } else {
                const unsigned* ph = h1b + rb + (mh << 9) + kh;
                for (;;) {
                    v4u x0, x1, x2, x3, h0, h1, h2, h3;
                    ld8cc(px, ph, x0, x1, x2, x3, h0, h1, h2, h3);
                    if ((tagdiff(x0, x1, tg) | tagdiff(x2, x3, tg) |
                         tagdiff(h0, h1, tg) | tagdiff(h2, h3, tg)) == 0) {
                        packlds(act_lds + (size_t)cx0 * 8, x0, x1);
                        packlds(act_lds + (size_t)(cx0 + 1) * 8, x2, x3);
                        packlds(act_lds + (size_t)ch0 * 8, h0, h1);
                        packlds(act_lds + (size_t)(ch0 + 1) * 8, h2, h3);
                        break;
                    }
                }
            }
        }
        __syncthreads();
        if (s == 1 && tid == 0)      // staging done: release ib slot (off-path)
            __hip_atomic_fetch_add(rc1, 1u, __ATOMIC_RELAXED, __HIP_MEMORY_SCOPE_AGENT);

        // ---- MFMA: gates[16 batch x 16 units] per wave, K=1024 ----
        v4f z = {0.f, 0.f, 0.f, 0.f};
        v4f acc0 = z, acc1 = z, acc2 = z, acc3 = z;
#pragma unroll
        for (int kt = 0; kt < 32; kt += 4) {
            v8s a0 = *(const v8s*)(act_lds + ((kt + 0) * 64 + l) * 8);
            v8s a1 = *(const v8s*)(act_lds + ((kt + 1) * 64 + l) * 8);
            v8s a2 = *(const v8s*)(act_lds + ((kt + 2) * 64 + l) * 8);
            v8s a3 = *(const v8s*)(act_lds + ((kt + 3) * 64 + l) * 8);
            acc0 = __builtin_amdgcn_mfma_f32_16x16x32_bf16(a0, wf[kt + 0], acc0, 0, 0, 0);
            acc1 = __builtin_amdgcn_mfma_f32_16x16x32_bf16(a1, wf[kt + 1], acc1, 0, 0, 0);
            acc2 = __builtin_amdgcn_mfma_f32_16x16x32_bf16(a2, wf[kt + 2], acc2, 0, 0, 0);
            acc3 = __builtin_amdgcn_mfma_f32_16x16x32_bf16(a3, wf[kt + 3], acc3, 0, 0, 0);
        }
        v4f af = (acc0 + acc1) + (acc2 + acc3);
#pragma unroll
        for (int r = 0; r < 4; ++r)
            gates_lds[q][quad * 4 + r][uh * 16 + l15] = af[r];
        __syncthreads();

        // ---- cell update: thread owns (batch cb, unit cu) ----
        float gi = gates_lds[0][cb][cu] + bias[0];
        float gf = gates_lds[1][cb][cu] + bias[1];
        float gg = gates_lds[2][cb][cu] + bias[2];
        float go = gates_lds[3][cb][cu] + bias[3];
        float ii = sigmoidf_(gi), ff = sigmoidf_(gf);
        float gv = tanhf_(gg),   oo = sigmoidf_(go);
        float cs = ff * creg + ii * gv;
        float hs = oo * tanhf_(cs);
        const bool msk = (t < len);
        if (msk) { creg = cs; hreg = hs; }

        // ---- EARLY h-store: issue before rc1 gate + barrier#3 ----
        const unsigned otg = (unsigned)tau;
        const int widx = wb + (cb << 9) + u0 + cu;
        stcc(myhb + widx, (((unsigned)(unsigned short)f2bf(hreg)) << 16) | otg);

        float i1s = 0.f;
        if (s == 0) {
            i1s = hs + xres;                            // candidate residual, per ref
        } else {
            int k  = u0 + cu;                           // staged bf16 i1 from LDS
            int cI = ((k >> 5) << 6) + (((k >> 3) & 3) << 4) + cb;
            unsigned short us = (unsigned short)act_lds[cI * 8 + (k & 7)];
            float i1 = __uint_as_float(((unsigned)us) << 16);
            out[(((size_t)(bg + cb) * TT + t) << 9) + u0 + cu] = msk ? (i1 + hs) : 0.f;
        }
        if (s == 0 && tid == 0 && tau >= 4) {           // ib slot anti-dep (usually free)
            unsigned need = 16u * (unsigned)(tau - 3);
            if (rcv < need) wait_ge(rc1, need);
        }
        __syncthreads();   // gate ibb store on anti-dep; protects act_lds/gates_lds reuse

        // ---- ibb store stays gated (s1-consumption anti-dep) ----
        if (s == 0)
            stcc(ibb + widx, (((unsigned)(unsigned short)f2bf(i1s)) << 16) | otg);
    }

    // ---- final h, c ----
    const size_t OH = (size_t)BB * TT * HH;
    const size_t hoff = OH + (size_t)s * BB * HH + ((size_t)(bg + cb) << 9) + u0 + cu;
    out[hoff] = hreg;
    out[hoff + (size_t)2 * BB * HH] = creg;
}

extern "C" void kernel_launch(void* const* d_in, const int* in_sizes, int n_in,
                              void* d_out, int out_size, void* d_ws, size_t ws_size,
                              hipStream_t stream) {
    const float* seq     = (const float*)d_in[0];
    const int*   seq_len = (const int*)d_in[1];
    const float* W_ih    = (const float*)d_in[2];
    const float* W_hh    = (const float*)d_in[3];
    const float* b_ih    = (const float*)d_in[4];
    const float* b_hh    = (const float*)d_in[5];
    float* out = (float*)d_out;

    hipMemsetAsync(d_ws, 0, 1024, stream);   // rc1 counters; data buffers are tag-guarded

    lstm_persistent_kernel<<<dim3(128), dim3(512), 0, stream>>>(
        seq, seq_len, W_ih, W_hh, b_ih, b_hh, out, (char*)d_ws);
}